// Round 1
// baseline (580.067 us; speedup 1.0000x reference)
//
#include <hip/hip_runtime.h>
#include <cmath>

// MNEMatch: B pairs of [N,D] fp32; S = x1 @ x2^T per pair; greedy max matching
// (N sequential global-argmax + row/col removal); out[b] = tanh(sum/N).
#define NN 256
#define DD 384

// ---------------- Kernel 1: batched S = A @ B^T (fp32, 64x64 tiles) --------
__global__ __launch_bounds__(256) void gemm_bt(const float* __restrict__ X1,
                                               const float* __restrict__ X2,
                                               float* __restrict__ S) {
  const int pair  = blockIdx.z;
  const int rbase = blockIdx.y * 64;
  const int cbase = blockIdx.x * 64;
  const float* A  = X1 + (size_t)pair * NN * DD;
  const float* Bm = X2 + (size_t)pair * NN * DD;

  __shared__ float As[64][17];   // +1 pad: conflict-free strided reads
  __shared__ float Bs[64][17];

  const int tid  = threadIdx.x;
  const int tx   = tid & 15;     // output col group
  const int ty   = tid >> 4;     // output row group
  const int lrow = tid >> 2;     // staging: row 0..63
  const int lk   = (tid & 3) << 2; // staging: k offset 0,4,8,12

  float acc[4][4] = {};

  for (int k0 = 0; k0 < DD; k0 += 16) {
    float4 av = *(const float4*)(A  + (size_t)(rbase + lrow) * DD + k0 + lk);
    float4 bv = *(const float4*)(Bm + (size_t)(cbase + lrow) * DD + k0 + lk);
    __syncthreads();
    As[lrow][lk+0] = av.x; As[lrow][lk+1] = av.y;
    As[lrow][lk+2] = av.z; As[lrow][lk+3] = av.w;
    Bs[lrow][lk+0] = bv.x; Bs[lrow][lk+1] = bv.y;
    Bs[lrow][lk+2] = bv.z; Bs[lrow][lk+3] = bv.w;
    __syncthreads();
#pragma unroll
    for (int kk = 0; kk < 16; ++kk) {
      float a[4], b[4];
#pragma unroll
      for (int i = 0; i < 4; ++i) a[i] = As[ty + 16 * i][kk];
#pragma unroll
      for (int j = 0; j < 4; ++j) b[j] = Bs[tx + 16 * j][kk];
#pragma unroll
      for (int i = 0; i < 4; ++i)
#pragma unroll
        for (int j = 0; j < 4; ++j)
          acc[i][j] += a[i] * b[j];
    }
  }

  float* Sp = S + (size_t)pair * NN * NN;
#pragma unroll
  for (int i = 0; i < 4; ++i)
#pragma unroll
    for (int j = 0; j < 4; ++j)
      Sp[(size_t)(rbase + ty + 16 * i) * NN + (cbase + tx + 16 * j)] = acc[i][j];
}

// ------------- Kernel 2: greedy matching, one block per pair ---------------
// Incremental argmax: rowmax/rowarg cached in LDS; per iteration a single
// wave argmaxes the 256 row maxima; only rows whose cached argmax column was
// just removed get rescanned (by whole waves, shuffle-reduced).
// Tie-break == jnp.argmax flat row-major: strict '>' in increasing index
// order per lane; (equal -> smaller index) across lanes.
__global__ __launch_bounds__(256) void greedy_match(const float* __restrict__ S,
                                                    float* __restrict__ out) {
  const int pair = blockIdx.x;
  const float* Sp = S + (size_t)pair * NN * NN;

  __shared__ float rowmax[NN];
  __shared__ int   rowarg[NN];
  __shared__ float colpen[NN];   // 0.0 alive, -inf dead (branchless mask)
  __shared__ int   dirty[NN];
  __shared__ int   ndirty;
  __shared__ int   s_bestc;

  const int tid = threadIdx.x;
  colpen[tid] = 0.0f;

  // init: thread t scans row t (all cols alive)
  {
    const float4* row = (const float4*)(Sp + (size_t)tid * NN);
    float best = -INFINITY; int barg = 0;
#pragma unroll 4
    for (int c4 = 0; c4 < NN / 4; ++c4) {
      float4 v = row[c4];
      int c = c4 * 4;
      if (v.x > best) { best = v.x; barg = c;     }
      if (v.y > best) { best = v.y; barg = c + 1; }
      if (v.z > best) { best = v.z; barg = c + 2; }
      if (v.w > best) { best = v.w; barg = c + 3; }
    }
    rowmax[tid] = best; rowarg[tid] = barg;
  }
  __syncthreads();

  float sum = 0.0f;  // live only in thread 0

  for (int it = 0; it < NN; ++it) {
    // --- wave 0: argmax over the 256 row maxima (no barriers inside) ---
    if (tid < 64) {
      float bv = -INFINITY; int br = -1;
#pragma unroll
      for (int i = 0; i < 4; ++i) {
        int r = tid + 64 * i;          // increasing r => strict '>' keeps min r
        float v = rowmax[r];
        if (v > bv) { bv = v; br = r; }
      }
#pragma unroll
      for (int m = 32; m >= 1; m >>= 1) {
        float ov = __shfl_xor(bv, m, 64);
        int   orr = __shfl_xor(br, m, 64);
        if (ov > bv || (ov == bv && orr < br)) { bv = ov; br = orr; }
      }
      if (tid == 0) {
        int bc = rowarg[br];
        sum += bv;                     // picked value S[br][bc]
        rowmax[br] = -INFINITY;        // kill row
        colpen[bc] = -INFINITY;        // kill col
        s_bestc = bc;
        ndirty = 0;
      }
    }
    __syncthreads();

    // --- mark rows whose cached argmax column just died ---
    const int bc = s_bestc;
    if (rowmax[tid] != -INFINITY && rowarg[tid] == bc) {
      int idx = atomicAdd(&ndirty, 1);
      dirty[idx] = tid;
    }
    __syncthreads();

    // --- rescan dirty rows: one wave per row ---
    const int nd = ndirty;
    const int wave = tid >> 6, lane = tid & 63;
    for (int i = wave; i < nd; i += 4) {
      const int r = dirty[i];
      const float* row = Sp + (size_t)r * NN;
      float bv = -INFINITY; int bcc = 0;
#pragma unroll
      for (int j = 0; j < 4; ++j) {
        int c = lane + 64 * j;         // increasing c per lane
        float v = row[c] + colpen[c];  // dead col => -inf
        if (v > bv) { bv = v; bcc = c; }
      }
#pragma unroll
      for (int m = 32; m >= 1; m >>= 1) {
        float ov = __shfl_xor(bv, m, 64);
        int   oc = __shfl_xor(bcc, m, 64);
        if (ov > bv || (ov == bv && oc < bcc)) { bv = ov; bcc = oc; }
      }
      if (lane == 0) { rowmax[r] = bv; rowarg[r] = bcc; }
    }
    __syncthreads();
  }

  if (tid == 0) out[pair] = tanhf(sum / (float)NN);
}

extern "C" void kernel_launch(void* const* d_in, const int* in_sizes, int n_in,
                              void* d_out, int out_size, void* d_ws, size_t ws_size,
                              hipStream_t stream) {
  const float* x1 = (const float*)d_in[0];
  const float* x2 = (const float*)d_in[1];
  float* out = (float*)d_out;
  float* S   = (float*)d_ws;           // needs B*N*N*4 = 32 MiB

  const int B = in_sizes[0] / (NN * DD);

  dim3 ggrid(NN / 64, NN / 64, B);     // 4 x 4 x 128 = 2048 blocks
  gemm_bt<<<ggrid, 256, 0, stream>>>(x1, x2, S);
  greedy_match<<<B, 256, 0, stream>>>(S, out);
}